// Round 4
// baseline (708.722 us; speedup 1.0000x reference)
//
#include <hip/hip_runtime.h>
#include <cstddef>

// Problem constants (match reference)
#define N_NODES 100000
#define N_EDGES 1600000
#define E_TOT   (N_EDGES + N_NODES)   // edges + self loops = 1,700,000
#define IN_DIM  64
#define HIDDEN  128
#define Z_DIM   64

// ---------------- CSR build ----------------

__global__ __launch_bounds__(256) void init_cnt_k(int* cnt, int n) {
    int i = blockIdx.x * 256 + threadIdx.x;
    if (i < n) cnt[i] = 1;   // self loop
}

__global__ __launch_bounds__(256) void count_k(const int* __restrict__ dst, int* cnt, int e) {
    int i = blockIdx.x * 256 + threadIdx.x;
    if (i < e) atomicAdd(&cnt[dst[i]], 1);
}

__global__ __launch_bounds__(256) void dinv_k(const int* __restrict__ cnt, float* __restrict__ dinv, int n) {
    int i = blockIdx.x * 256 + threadIdx.x;
    if (i < n) dinv[i] = rsqrtf((float)cnt[i]);   // cnt >= 1 always
}

__global__ __launch_bounds__(256) void scan_block_k(const int* __restrict__ cnt, int* __restrict__ rowptr,
                                                    int* __restrict__ bsum, int n) {
    __shared__ int s[256];
    int tid = threadIdx.x;
    int i = blockIdx.x * 256 + tid;
    int v = (i < n) ? cnt[i] : 0;
    s[tid] = v;
    __syncthreads();
#pragma unroll
    for (int off = 1; off < 256; off <<= 1) {
        int t = (tid >= off) ? s[tid - off] : 0;
        __syncthreads();
        s[tid] += t;
        __syncthreads();
    }
    if (i < n) rowptr[i] = s[tid] - v;        // exclusive within block
    if (tid == 255) bsum[blockIdx.x] = s[255];
}

__global__ __launch_bounds__(512) void scan_bsum_k(int* bsum, int nb) {
    __shared__ int s[512];
    int tid = threadIdx.x;
    int v = (tid < nb) ? bsum[tid] : 0;
    s[tid] = v;
    __syncthreads();
#pragma unroll
    for (int off = 1; off < 512; off <<= 1) {
        int t = (tid >= off) ? s[tid - off] : 0;
        __syncthreads();
        s[tid] += t;
        __syncthreads();
    }
    if (tid < nb) bsum[tid] = s[tid] - v;     // exclusive
}

__global__ __launch_bounds__(256) void scan_add_k(int* __restrict__ rowptr, const int* __restrict__ bsum,
                                                  int* __restrict__ cursor, int n, int etot) {
    int i = blockIdx.x * 256 + threadIdx.x;
    if (i < n) {
        int val = rowptr[i] + bsum[blockIdx.x];
        rowptr[i] = val;
        cursor[i] = val;
    }
    if (i == 0) rowptr[n] = etot;
}

__global__ __launch_bounds__(256) void fill_k(const int* __restrict__ src, const int* __restrict__ dst,
                                              const float* __restrict__ dinv, int* cursor,
                                              int* __restrict__ col, float* __restrict__ nrm,
                                              int e, int n) {
    int i = blockIdx.x * 256 + threadIdx.x;
    if (i < e) {
        int s = src[i], d = dst[i];
        int p = atomicAdd(&cursor[d], 1);
        col[p] = s;
        nrm[p] = dinv[s] * dinv[d];
    } else if (i < e + n) {
        int v = i - e;
        int p = atomicAdd(&cursor[v], 1);
        col[p] = v;
        float dv = dinv[v];
        nrm[p] = dv * dv;
    }
}

// ---------------- Aggregation (gather): one wave per node, multi-edge float4 ----------------
// DIM=128: row = 32 float4; lanes split in 2 halves (sub=lane>>5), each half covers one edge's
//   row -> one global_load_dwordx4 per wave serves 2 edges (1 KB). Final shfl_xor(32) combine.
// DIM=64:  row = 16 float4; 4 quarter-waves (sub=lane>>4) -> 4 edges per load instr.
//   Final shfl_xor(32)+shfl_xor(16) combine. 8 edges in flight per iteration in both cases.

template <int DIM>
__global__ __launch_bounds__(256) void agg_k(const float* __restrict__ H, const int* __restrict__ rowptr,
                                             const int* __restrict__ col, const float* __restrict__ nrm,
                                             float* __restrict__ out, int n) {
    int node = (int)((blockIdx.x * 256 + threadIdx.x) >> 6);
    if (node >= n) return;
    int lane = threadIdx.x & 63;
    int beg = rowptr[node], end = rowptr[node + 1];
    const float4* H4 = (const float4*)H;

    float4 acc; acc.x = 0.f; acc.y = 0.f; acc.z = 0.f; acc.w = 0.f;

    if constexpr (DIM == 128) {
        constexpr int RV = 32;           // float4 per row
        int sub = lane >> 5;             // 0..1: which edge of the pair
        int fl  = lane & 31;             // float4 index within row
        int j = beg;
        for (; j + 8 <= end; j += 8) {
#pragma unroll
            for (int p = 0; p < 4; p++) {
                int   s = col[j + 2 * p + sub];
                float w = nrm[j + 2 * p + sub];
                float4 v = H4[(size_t)s * RV + fl];
                acc.x += w * v.x; acc.y += w * v.y; acc.z += w * v.z; acc.w += w * v.w;
            }
        }
        for (; j + 2 <= end; j += 2) {
            int   s = col[j + sub];
            float w = nrm[j + sub];
            float4 v = H4[(size_t)s * RV + fl];
            acc.x += w * v.x; acc.y += w * v.y; acc.z += w * v.z; acc.w += w * v.w;
        }
        if (j < end) {                   // rem == 1: sub=1 half contributes 0
            int   s = (sub == 0) ? col[j] : col[beg];
            float w = (sub == 0) ? nrm[j] : 0.f;
            float4 v = H4[(size_t)s * RV + fl];
            acc.x += w * v.x; acc.y += w * v.y; acc.z += w * v.z; acc.w += w * v.w;
        }
        // combine halves: lane L += lane L^32
        acc.x += __shfl_xor(acc.x, 32);
        acc.y += __shfl_xor(acc.y, 32);
        acc.z += __shfl_xor(acc.z, 32);
        acc.w += __shfl_xor(acc.w, 32);
        if (sub == 0) ((float4*)out)[(size_t)node * RV + fl] = acc;
    } else {
        constexpr int RV = 16;           // float4 per row
        int sub = lane >> 4;             // 0..3: which edge of the quad
        int fl  = lane & 15;
        int j = beg;
        for (; j + 8 <= end; j += 8) {
#pragma unroll
            for (int p = 0; p < 2; p++) {
                int   s = col[j + 4 * p + sub];
                float w = nrm[j + 4 * p + sub];
                float4 v = H4[(size_t)s * RV + fl];
                acc.x += w * v.x; acc.y += w * v.y; acc.z += w * v.z; acc.w += w * v.w;
            }
        }
        for (; j + 4 <= end; j += 4) {
            int   s = col[j + sub];
            float w = nrm[j + sub];
            float4 v = H4[(size_t)s * RV + fl];
            acc.x += w * v.x; acc.y += w * v.y; acc.z += w * v.z; acc.w += w * v.w;
        }
        if (j < end) {                   // rem in 1..3, one masked quad pass
            bool  ok = (j + sub) < end;
            int   s = ok ? col[j + sub] : col[beg];
            float w = ok ? nrm[j + sub] : 0.f;
            float4 v = H4[(size_t)s * RV + fl];
            acc.x += w * v.x; acc.y += w * v.y; acc.z += w * v.z; acc.w += w * v.w;
        }
        acc.x += __shfl_xor(acc.x, 32);
        acc.y += __shfl_xor(acc.y, 32);
        acc.z += __shfl_xor(acc.z, 32);
        acc.w += __shfl_xor(acc.w, 32);
        acc.x += __shfl_xor(acc.x, 16);
        acc.y += __shfl_xor(acc.y, 16);
        acc.z += __shfl_xor(acc.z, 16);
        acc.w += __shfl_xor(acc.w, 16);
        if (sub == 0) ((float4*)out)[(size_t)node * RV + fl] = acc;
    }
}

// ---------------- Dense layer, F=128 outputs, conflict-free LDS, 4n x 16f per thread ----
// Block = 256 threads, 128 nodes/block. Thread t: fg=t&7 owns feats fg*4+32*j (j=0..3),
// mg=t>>3 owns local nodes mg*4+r (r=0..3). Ws ds_read_b128: 8 distinct addrs (fg) at
// banks 4fg..4fg+3 = all 32 banks, 8-lane broadcast each -> conflict-free. As (stride 33)
// ds_read_b32: broadcast -> conflict-free. VALU-bound by design; acc = 64 VGPR.
// DUAL: output cols 0..63 = Wa/ba -> Ca, 64..127 = Wb/bb -> Cb (fused mu/logvar heads).

template <int K, bool RELU, bool DUAL>
__global__ __launch_bounds__(256, 3) void gemm128_k(const float* __restrict__ A,
                                                    const float* __restrict__ Wa, const float* __restrict__ Wb,
                                                    const float* __restrict__ ba, const float* __restrict__ bb,
                                                    float* __restrict__ Ca, float* __restrict__ Cb, int n) {
    constexpr int F  = 128;
    constexpr int NT = 128;          // nodes per block
    constexpr int KC = 32;           // K chunk
    constexpr int AS = 33;           // As row stride (floats)
    __shared__ __align__(16) float Ws[KC * F];   // 16 KB
    __shared__ float As[NT * AS];                // ~16.5 KB

    int t  = threadIdx.x;
    int fg = t & 7;
    int mg = t >> 3;
    int m0 = blockIdx.x * NT;

    float4 acc[4][4];                // [r][j]
#pragma unroll
    for (int r = 0; r < 4; r++)
#pragma unroll
        for (int j = 0; j < 4; j++) { acc[r][j].x = 0.f; acc[r][j].y = 0.f; acc[r][j].z = 0.f; acc[r][j].w = 0.f; }

    for (int kc = 0; kc < K; kc += KC) {
        // stage Ws chunk: KC*F/4 = 1024 float4, 4 per thread
        for (int e = t; e < KC * F / 4; e += 256) {
            float4 w;
            if (!DUAL) {
                w = ((const float4*)Wa)[(size_t)kc * (F / 4) + e];
            } else {
                int r = e >> 5;              // k row within chunk
                int c = (e & 31) * 4;        // float col 0..127
                w = (c < 64) ? *(const float4*)&Wa[(size_t)(kc + r) * 64 + c]
                             : *(const float4*)&Wb[(size_t)(kc + r) * 64 + (c - 64)];
            }
            ((float4*)Ws)[e] = w;
        }
        // stage As chunk: NT*KC floats, coalesced float4 reads, scalar LDS writes (pad 33)
        for (int e = t; e < NT * KC / 4; e += 256) {
            int r = e >> 3;                  // / (KC/4)
            int c = (e & 7) * 4;             // float col within chunk
            float4 v;
            if (m0 + r < n) v = *(const float4*)&A[(size_t)(m0 + r) * K + kc + c];
            else { v.x = 0.f; v.y = 0.f; v.z = 0.f; v.w = 0.f; }
            float* p = &As[r * AS + c];
            p[0] = v.x; p[1] = v.y; p[2] = v.z; p[3] = v.w;
        }
        __syncthreads();

#pragma unroll 4
        for (int k = 0; k < KC; k++) {
            float a0 = As[(mg * 4 + 0) * AS + k];
            float a1 = As[(mg * 4 + 1) * AS + k];
            float a2 = As[(mg * 4 + 2) * AS + k];
            float a3 = As[(mg * 4 + 3) * AS + k];
#pragma unroll
            for (int j = 0; j < 4; j++) {
                float4 w = *(const float4*)&Ws[k * F + fg * 4 + 32 * j];
                acc[0][j].x += a0 * w.x; acc[0][j].y += a0 * w.y; acc[0][j].z += a0 * w.z; acc[0][j].w += a0 * w.w;
                acc[1][j].x += a1 * w.x; acc[1][j].y += a1 * w.y; acc[1][j].z += a1 * w.z; acc[1][j].w += a1 * w.w;
                acc[2][j].x += a2 * w.x; acc[2][j].y += a2 * w.y; acc[2][j].z += a2 * w.z; acc[2][j].w += a2 * w.w;
                acc[3][j].x += a3 * w.x; acc[3][j].y += a3 * w.y; acc[3][j].z += a3 * w.z; acc[3][j].w += a3 * w.w;
            }
        }
        __syncthreads();
    }

    // epilogue: bias + optional relu; DUAL splits cols 0..63 / 64..127
#pragma unroll
    for (int r = 0; r < 4; r++) {
        int node = m0 + mg * 4 + r;
        if (node >= n) break;
#pragma unroll
        for (int j = 0; j < 4; j++) {
            int f = fg * 4 + 32 * j;
            float4 v = acc[r][j];
            const float* bp;
            float* cp;
            int fo;
            if (!DUAL) {
                bp = ba; cp = Ca + (size_t)node * F; fo = f;
            } else if (j < 2) {              // f < 64
                bp = ba; cp = Ca + (size_t)node * 64; fo = f;
            } else {
                bp = bb; cp = Cb + (size_t)node * 64; fo = f - 64;
            }
            v.x += bp[fo + 0]; v.y += bp[fo + 1]; v.z += bp[fo + 2]; v.w += bp[fo + 3];
            if (RELU) {
                v.x = fmaxf(v.x, 0.f); v.y = fmaxf(v.y, 0.f);
                v.z = fmaxf(v.z, 0.f); v.w = fmaxf(v.w, 0.f);
            }
            *(float4*)&cp[fo] = v;
        }
    }
}

// ---------------- launch ----------------

extern "C" void kernel_launch(void* const* d_in, const int* in_sizes, int n_in,
                              void* d_out, int out_size, void* d_ws, size_t ws_size,
                              hipStream_t stream) {
    const int N = N_NODES, E = N_EDGES, ETOT = E_TOT;

    const float* x    = (const float*)d_in[0];
    const int*   ei   = (const int*)d_in[1];
    const int*   srcA = ei;
    const int*   dstA = ei + E;
    const float* W1   = (const float*)d_in[2];
    const float* b1   = (const float*)d_in[3];
    const float* W2   = (const float*)d_in[4];
    const float* b2   = (const float*)d_in[5];
    const float* Wmu  = (const float*)d_in[6];
    const float* bmu  = (const float*)d_in[7];
    const float* Wlv  = (const float*)d_in[8];
    const float* blv  = (const float*)d_in[9];
    float* out = (float*)d_out;

    // workspace carve-out (~117 MB)
    char* ws = (char*)d_ws;
    size_t o = 0;
    auto alloc = [&](size_t bytes) -> void* {
        o = (o + 255) & ~(size_t)255;
        void* p = ws + o;
        o += bytes;
        return p;
    };
    int*   cnt    = (int*)alloc((size_t)N * 4);          // deg counts, later cursor
    int*   rowptr = (int*)alloc((size_t)(N + 1) * 4);
    float* dinv   = (float*)alloc((size_t)N * 4);
    int*   bsum   = (int*)alloc(512 * 4);
    int*   col    = (int*)alloc((size_t)ETOT * 4);
    float* nrm    = (float*)alloc((size_t)ETOT * 4);
    float* agg    = (float*)alloc((size_t)N * HIDDEN * 4);
    float* h      = (float*)alloc((size_t)N * HIDDEN * 4);
    (void)ws_size;

    const int gN = (N + 255) / 256;          // 391
    const int gE = (E + 255) / 256;          // 6250
    const int gT = (ETOT + 255) / 256;       // 6641
    const int gAgg = (N + 3) / 4;            // 25000 (4 nodes/block)
    const int gGemm = (N + 127) / 128;       // 782

    // CSR build
    init_cnt_k<<<gN, 256, 0, stream>>>(cnt, N);
    count_k<<<gE, 256, 0, stream>>>(dstA, cnt, E);
    dinv_k<<<gN, 256, 0, stream>>>(cnt, dinv, N);
    scan_block_k<<<gN, 256, 0, stream>>>(cnt, rowptr, bsum, N);
    scan_bsum_k<<<1, 512, 0, stream>>>(bsum, gN);
    scan_add_k<<<gN, 256, 0, stream>>>(rowptr, bsum, cnt /*cursor*/, N, ETOT);
    fill_k<<<gT, 256, 0, stream>>>(srcA, dstA, dinv, cnt, col, nrm, E, N);

    // layer 1: h = relu(Agg(x) @ W1 + b1)      (aggregate in 64-dim!)
    agg_k<64><<<gAgg, 256, 0, stream>>>(x, rowptr, col, nrm, agg, N);
    gemm128_k<64, true, false><<<gGemm, 256, 0, stream>>>(agg, W1, nullptr, b1, nullptr, h, nullptr, N);

    // layer 2: h = relu(Agg(h) @ W2 + b2)
    agg_k<128><<<gAgg, 256, 0, stream>>>(h, rowptr, col, nrm, agg, N);
    gemm128_k<128, true, false><<<gGemm, 256, 0, stream>>>(agg, W2, nullptr, b2, nullptr, h, nullptr, N);

    // heads: aggregate once, ONE fused GEMM (cols 0..63 = mu, 64..127 = logvar)
    agg_k<128><<<gAgg, 256, 0, stream>>>(h, rowptr, col, nrm, agg, N);
    gemm128_k<128, false, true><<<gGemm, 256, 0, stream>>>(agg, Wmu, Wlv, bmu, blv,
                                                           out, out + (size_t)N * Z_DIM, N);
}

// Round 5
// 685.836 us; speedup vs baseline: 1.0334x; 1.0334x over previous
//
#include <hip/hip_runtime.h>
#include <cstddef>

// Problem constants (match reference)
#define N_NODES 100000
#define N_EDGES 1600000
#define E_TOT   (N_EDGES + N_NODES)   // edges + self loops = 1,700,000
#define IN_DIM  64
#define HIDDEN  128
#define Z_DIM   64

// ---------------- CSR build ----------------

__global__ __launch_bounds__(256) void init_cnt_k(int* cnt, int n) {
    int i = blockIdx.x * 256 + threadIdx.x;
    if (i < n) cnt[i] = 1;   // self loop
}

__global__ __launch_bounds__(256) void count_k(const int* __restrict__ dst, int* cnt, int e) {
    int i = blockIdx.x * 256 + threadIdx.x;
    if (i < e) atomicAdd(&cnt[dst[i]], 1);
}

__global__ __launch_bounds__(256) void dinv_k(const int* __restrict__ cnt, float* __restrict__ dinv, int n) {
    int i = blockIdx.x * 256 + threadIdx.x;
    if (i < n) dinv[i] = rsqrtf((float)cnt[i]);   // cnt >= 1 always
}

__global__ __launch_bounds__(256) void scan_block_k(const int* __restrict__ cnt, int* __restrict__ rowptr,
                                                    int* __restrict__ bsum, int n) {
    __shared__ int s[256];
    int tid = threadIdx.x;
    int i = blockIdx.x * 256 + tid;
    int v = (i < n) ? cnt[i] : 0;
    s[tid] = v;
    __syncthreads();
#pragma unroll
    for (int off = 1; off < 256; off <<= 1) {
        int t = (tid >= off) ? s[tid - off] : 0;
        __syncthreads();
        s[tid] += t;
        __syncthreads();
    }
    if (i < n) rowptr[i] = s[tid] - v;        // exclusive within block
    if (tid == 255) bsum[blockIdx.x] = s[255];
}

__global__ __launch_bounds__(512) void scan_bsum_k(int* bsum, int nb) {
    __shared__ int s[512];
    int tid = threadIdx.x;
    int v = (tid < nb) ? bsum[tid] : 0;
    s[tid] = v;
    __syncthreads();
#pragma unroll
    for (int off = 1; off < 512; off <<= 1) {
        int t = (tid >= off) ? s[tid - off] : 0;
        __syncthreads();
        s[tid] += t;
        __syncthreads();
    }
    if (tid < nb) bsum[tid] = s[tid] - v;     // exclusive
}

__global__ __launch_bounds__(256) void scan_add_k(int* __restrict__ rowptr, const int* __restrict__ bsum,
                                                  int* __restrict__ cursor, int n, int etot) {
    int i = blockIdx.x * 256 + threadIdx.x;
    if (i < n) {
        int val = rowptr[i] + bsum[blockIdx.x];
        rowptr[i] = val;
        cursor[i] = val;
    }
    if (i == 0) rowptr[n] = etot;
}

__global__ __launch_bounds__(256) void fill_k(const int* __restrict__ src, const int* __restrict__ dst,
                                              const float* __restrict__ dinv, int* cursor,
                                              int* __restrict__ col, float* __restrict__ nrm,
                                              int e, int n) {
    int i = blockIdx.x * 256 + threadIdx.x;
    if (i < e) {
        int s = src[i], d = dst[i];
        int p = atomicAdd(&cursor[d], 1);
        col[p] = s;
        nrm[p] = dinv[s] * dinv[d];
    } else if (i < e + n) {
        int v = i - e;
        int p = atomicAdd(&cursor[v], 1);
        col[p] = v;
        float dv = dinv[v];
        nrm[p] = dv * dv;
    }
}

// ---------------- Aggregation (gather): one wave per node, deep-MLP masked iterations ------
// DIM=128: 16 edges/iter, 2 half-waves -> 8 dwordx4 in flight (8 KB/wave).
// DIM=64:  32 edges/iter, 4 quarter-waves -> 8 dwordx4 in flight.
// OOB edges within an iteration are clamp-indexed with weight 0 (beg<end always: self-loop).

template <int DIM>
__global__ __launch_bounds__(256) void agg_k(const float* __restrict__ H, const int* __restrict__ rowptr,
                                             const int* __restrict__ col, const float* __restrict__ nrm,
                                             float* __restrict__ out, int n) {
    int node = (int)((blockIdx.x * 256 + threadIdx.x) >> 6);
    if (node >= n) return;
    int lane = threadIdx.x & 63;
    int beg = rowptr[node], end = rowptr[node + 1];
    const float4* H4 = (const float4*)H;

    float4 acc; acc.x = 0.f; acc.y = 0.f; acc.z = 0.f; acc.w = 0.f;

    if constexpr (DIM == 128) {
        constexpr int RV = 32;
        int sub = lane >> 5;             // 0..1: which edge of a pair
        int fl  = lane & 31;
        for (int j = beg; j < end; j += 16) {
            int   s[8]; float w[8];
#pragma unroll
            for (int p = 0; p < 8; p++) {
                int idx = j + 2 * p + sub;
                int ci  = idx < end ? idx : beg;
                s[p] = col[ci];
                w[p] = idx < end ? nrm[ci] : 0.f;
            }
#pragma unroll
            for (int p = 0; p < 8; p++) {
                float4 v = H4[(size_t)s[p] * RV + fl];
                acc.x += w[p] * v.x; acc.y += w[p] * v.y;
                acc.z += w[p] * v.z; acc.w += w[p] * v.w;
            }
        }
        acc.x += __shfl_xor(acc.x, 32);
        acc.y += __shfl_xor(acc.y, 32);
        acc.z += __shfl_xor(acc.z, 32);
        acc.w += __shfl_xor(acc.w, 32);
        if (sub == 0) ((float4*)out)[(size_t)node * RV + fl] = acc;
    } else {
        constexpr int RV = 16;
        int sub = lane >> 4;             // 0..3: which edge of a quad
        int fl  = lane & 15;
        for (int j = beg; j < end; j += 32) {
            int   s[8]; float w[8];
#pragma unroll
            for (int p = 0; p < 8; p++) {
                int idx = j + 4 * p + sub;
                int ci  = idx < end ? idx : beg;
                s[p] = col[ci];
                w[p] = idx < end ? nrm[ci] : 0.f;
            }
#pragma unroll
            for (int p = 0; p < 8; p++) {
                float4 v = H4[(size_t)s[p] * RV + fl];
                acc.x += w[p] * v.x; acc.y += w[p] * v.y;
                acc.z += w[p] * v.z; acc.w += w[p] * v.w;
            }
        }
        acc.x += __shfl_xor(acc.x, 32);
        acc.y += __shfl_xor(acc.y, 32);
        acc.z += __shfl_xor(acc.z, 32);
        acc.w += __shfl_xor(acc.w, 32);
        acc.x += __shfl_xor(acc.x, 16);
        acc.y += __shfl_xor(acc.y, 16);
        acc.z += __shfl_xor(acc.z, 16);
        acc.w += __shfl_xor(acc.w, 16);
        if (sub == 0) ((float4*)out)[(size_t)node * RV + fl] = acc;
    }
}

// ---------------- Dense layer: whole W in LDS, ONE barrier, A streamed from global --------
// Block = 256 threads, 128 nodes. Thread: fg=t&7 owns feats fg*4+32*j (float4 idx fg+8j ->
// byte 16*(fg+8j) -> banks 4fg..4fg+3, 8-lane broadcast: conflict-free). mg=t>>3 owns rows
// mg*4+r. A row read by 8 threads of same wave -> L1 broadcast; A streamed once (memory floor
// ~100 MB per GEMM). No As tile, no K-loop barriers.
// DUAL: output cols 0..63 = Wa/ba -> Ca, 64..127 = Wb/bb -> Cb (fused mu/logvar heads).

template <int K, bool RELU, bool DUAL>
__global__ __launch_bounds__(256, 3) void gemm128_k(const float* __restrict__ A,
                                                    const float* __restrict__ Wa, const float* __restrict__ Wb,
                                                    const float* __restrict__ ba, const float* __restrict__ bb,
                                                    float* __restrict__ Ca, float* __restrict__ Cb, int n) {
    constexpr int F  = 128;
    constexpr int NT = 128;          // nodes per block
    __shared__ __align__(16) float Ws[K * F];    // 32 KB (K=64) / 64 KB (K=128)

    int t  = threadIdx.x;
    int fg = t & 7;
    int mg = t >> 3;
    int m0 = blockIdx.x * NT;

    // stage whole W (K*F/4 float4, coalesced)
    for (int e = t; e < K * F / 4; e += 256) {
        float4 w;
        if (!DUAL) {
            w = ((const float4*)Wa)[e];
        } else {
            int r = e >> 5;              // k row
            int c = (e & 31) * 4;        // float col 0..127
            w = (c < 64) ? *(const float4*)&Wa[(size_t)r * 64 + c]
                         : *(const float4*)&Wb[(size_t)r * 64 + (c - 64)];
        }
        ((float4*)Ws)[e] = w;
    }
    __syncthreads();

    // row pointers (clamped; garbage rows computed but not stored)
    const float* Ap[4];
#pragma unroll
    for (int r = 0; r < 4; r++) {
        int row = m0 + mg * 4 + r;
        Ap[r] = A + (size_t)(row < n ? row : (n - 1)) * K;
    }

    float4 acc[4][4];                // [r][j]
#pragma unroll
    for (int r = 0; r < 4; r++)
#pragma unroll
        for (int j = 0; j < 4; j++) { acc[r][j].x = 0.f; acc[r][j].y = 0.f; acc[r][j].z = 0.f; acc[r][j].w = 0.f; }

    for (int k4 = 0; k4 < K; k4 += 4) {
        float4 av[4];
#pragma unroll
        for (int r = 0; r < 4; r++) av[r] = *(const float4*)&Ap[r][k4];
#pragma unroll
        for (int kk = 0; kk < 4; kk++) {
            float a0 = ((const float*)&av[0])[kk];
            float a1 = ((const float*)&av[1])[kk];
            float a2 = ((const float*)&av[2])[kk];
            float a3 = ((const float*)&av[3])[kk];
#pragma unroll
            for (int j = 0; j < 4; j++) {
                float4 w = ((const float4*)Ws)[(k4 + kk) * (F / 4) + fg + 8 * j];
                acc[0][j].x += a0 * w.x; acc[0][j].y += a0 * w.y; acc[0][j].z += a0 * w.z; acc[0][j].w += a0 * w.w;
                acc[1][j].x += a1 * w.x; acc[1][j].y += a1 * w.y; acc[1][j].z += a1 * w.z; acc[1][j].w += a1 * w.w;
                acc[2][j].x += a2 * w.x; acc[2][j].y += a2 * w.y; acc[2][j].z += a2 * w.z; acc[2][j].w += a2 * w.w;
                acc[3][j].x += a3 * w.x; acc[3][j].y += a3 * w.y; acc[3][j].z += a3 * w.z; acc[3][j].w += a3 * w.w;
            }
        }
    }

    // epilogue: bias + optional relu; DUAL splits cols 0..63 / 64..127
#pragma unroll
    for (int r = 0; r < 4; r++) {
        int node = m0 + mg * 4 + r;
        if (node >= n) break;
#pragma unroll
        for (int j = 0; j < 4; j++) {
            int f = fg * 4 + 32 * j;
            float4 v = acc[r][j];
            const float* bp;
            float* cp;
            int fo;
            if (!DUAL) {
                bp = ba; cp = Ca + (size_t)node * F; fo = f;
            } else if (j < 2) {              // f < 64
                bp = ba; cp = Ca + (size_t)node * 64; fo = f;
            } else {
                bp = bb; cp = Cb + (size_t)node * 64; fo = f - 64;
            }
            v.x += bp[fo + 0]; v.y += bp[fo + 1]; v.z += bp[fo + 2]; v.w += bp[fo + 3];
            if (RELU) {
                v.x = fmaxf(v.x, 0.f); v.y = fmaxf(v.y, 0.f);
                v.z = fmaxf(v.z, 0.f); v.w = fmaxf(v.w, 0.f);
            }
            *(float4*)&cp[fo] = v;
        }
    }
}

// ---------------- launch ----------------

extern "C" void kernel_launch(void* const* d_in, const int* in_sizes, int n_in,
                              void* d_out, int out_size, void* d_ws, size_t ws_size,
                              hipStream_t stream) {
    const int N = N_NODES, E = N_EDGES, ETOT = E_TOT;

    const float* x    = (const float*)d_in[0];
    const int*   ei   = (const int*)d_in[1];
    const int*   srcA = ei;
    const int*   dstA = ei + E;
    const float* W1   = (const float*)d_in[2];
    const float* b1   = (const float*)d_in[3];
    const float* W2   = (const float*)d_in[4];
    const float* b2   = (const float*)d_in[5];
    const float* Wmu  = (const float*)d_in[6];
    const float* bmu  = (const float*)d_in[7];
    const float* Wlv  = (const float*)d_in[8];
    const float* blv  = (const float*)d_in[9];
    float* out = (float*)d_out;

    // workspace carve-out (~117 MB)
    char* ws = (char*)d_ws;
    size_t o = 0;
    auto alloc = [&](size_t bytes) -> void* {
        o = (o + 255) & ~(size_t)255;
        void* p = ws + o;
        o += bytes;
        return p;
    };
    int*   cnt    = (int*)alloc((size_t)N * 4);          // deg counts, later cursor
    int*   rowptr = (int*)alloc((size_t)(N + 1) * 4);
    float* dinv   = (float*)alloc((size_t)N * 4);
    int*   bsum   = (int*)alloc(512 * 4);
    int*   col    = (int*)alloc((size_t)ETOT * 4);
    float* nrm    = (float*)alloc((size_t)ETOT * 4);
    float* agg    = (float*)alloc((size_t)N * HIDDEN * 4);
    float* h      = (float*)alloc((size_t)N * HIDDEN * 4);
    (void)ws_size;

    const int gN = (N + 255) / 256;          // 391
    const int gE = (E + 255) / 256;          // 6250
    const int gT = (ETOT + 255) / 256;       // 6641
    const int gAgg = (N + 3) / 4;            // 25000 (4 nodes/block)
    const int gGemm = (N + 127) / 128;       // 782

    // CSR build
    init_cnt_k<<<gN, 256, 0, stream>>>(cnt, N);
    count_k<<<gE, 256, 0, stream>>>(dstA, cnt, E);
    dinv_k<<<gN, 256, 0, stream>>>(cnt, dinv, N);
    scan_block_k<<<gN, 256, 0, stream>>>(cnt, rowptr, bsum, N);
    scan_bsum_k<<<1, 512, 0, stream>>>(bsum, gN);
    scan_add_k<<<gN, 256, 0, stream>>>(rowptr, bsum, cnt /*cursor*/, N, ETOT);
    fill_k<<<gT, 256, 0, stream>>>(srcA, dstA, dinv, cnt, col, nrm, E, N);

    // layer 1: h = relu(Agg(x) @ W1 + b1)      (aggregate in 64-dim!)
    agg_k<64><<<gAgg, 256, 0, stream>>>(x, rowptr, col, nrm, agg, N);
    gemm128_k<64, true, false><<<gGemm, 256, 0, stream>>>(agg, W1, nullptr, b1, nullptr, h, nullptr, N);

    // layer 2: h = relu(Agg(h) @ W2 + b2)
    agg_k<128><<<gAgg, 256, 0, stream>>>(h, rowptr, col, nrm, agg, N);
    gemm128_k<128, true, false><<<gGemm, 256, 0, stream>>>(agg, W2, nullptr, b2, nullptr, h, nullptr, N);

    // heads: aggregate once, ONE fused GEMM (cols 0..63 = mu, 64..127 = logvar)
    agg_k<128><<<gAgg, 256, 0, stream>>>(h, rowptr, col, nrm, agg, N);
    gemm128_k<128, false, true><<<gGemm, 256, 0, stream>>>(agg, Wmu, Wlv, bmu, blv,
                                                           out, out + (size_t)N * Z_DIM, N);
}